// Round 5
// baseline (149.119 us; speedup 1.0000x reference)
//
#include <hip/hip_runtime.h>
#include <hip/hip_bf16.h>

#define BB  2
#define CC  64
#define HH  256
#define WW  320
#define NNB 9
#define PIX_PER_B (NNB * HH * WW)   // 737280
#define PIX_PER_BLOCK 256           // 256 threads, 2 lanes/pixel, 2 px/thread

typedef unsigned int uint;

// ---------------------------------------------------------------------------
// Kernel 1: transpose [B,C,H,W] fp32 -> [B,H,W,C] bf16 (channel-contiguous)
// ---------------------------------------------------------------------------
__global__ __launch_bounds__(256) void fw_transpose(const float* __restrict__ feat,
                                                    ushort* __restrict__ featT) {
  __shared__ float tile[64][65];
  const int b = blockIdx.z, h = blockIdx.y, w0 = blockIdx.x * 64;
  const int tid = threadIdx.x;
#pragma unroll
  for (int it = 0; it < 16; ++it) {
    int idx = it * 256 + tid;
    int c = idx >> 6, w = idx & 63;
    tile[c][w] = feat[((b * CC + c) * HH + h) * WW + w0 + w];
  }
  __syncthreads();
#pragma unroll
  for (int it = 0; it < 16; ++it) {
    int idx = it * 256 + tid;
    int w = idx >> 6, c = idx & 63;
    __hip_bfloat16 v = __float2bfloat16(tile[c][w]);
    featT[((b * HH + h) * WW + w0 + w) * 64 + c] = *(ushort*)&v;
  }
}

__device__ __forceinline__ float blo(uint u) { return __uint_as_float(u << 16); }
__device__ __forceinline__ float bhi(uint u) { return __uint_as_float(u & 0xffff0000u); }

// ---------------------------------------------------------------------------
// Weight folding into LDS (BN folded to affine).
// ---------------------------------------------------------------------------
#define FOLD_WEIGHTS()                                                         \
  __shared__ float sW0[16 * 8], sB0[16], sW1[8 * 16], sB1[8], sSW[8], sSB[1];  \
  {                                                                            \
    const int tt = threadIdx.x;                                                \
    if (tt < 16) {                                                             \
      float a = bn0_g[tt] * rsqrtf(bn0_v[tt] + 1e-5f);                         \
      sB0[tt] = bn0_b[tt] - bn0_m[tt] * a;                                     \
      _Pragma("unroll") for (int g = 0; g < 8; ++g)                            \
          sW0[tt * 8 + g] = conv0_w[tt * 8 + g] * a;                           \
    } else if (tt < 24) {                                                      \
      int o = tt - 16;                                                         \
      float a = bn1_g[o] * rsqrtf(bn1_v[o] + 1e-5f);                           \
      sB1[o] = bn1_b[o] - bn1_m[o] * a;                                        \
      _Pragma("unroll") for (int c = 0; c < 16; ++c)                           \
          sW1[o * 16 + c] = conv1_w[o * 16 + c] * a;                           \
    } else if (tt < 32) {                                                      \
      sSW[tt - 24] = sim_w[tt - 24];                                           \
      if (tt == 31) sSB[0] = sim_b[0];                                         \
    }                                                                          \
  }                                                                            \
  __syncthreads();

#define WARGS                                                                   \
  const float* __restrict__ conv0_w, const float* __restrict__ bn0_g,           \
  const float* __restrict__ bn0_b, const float* __restrict__ bn0_m,             \
  const float* __restrict__ bn0_v, const float* __restrict__ conv1_w,           \
  const float* __restrict__ bn1_g, const float* __restrict__ bn1_b,             \
  const float* __restrict__ bn1_m, const float* __restrict__ bn1_v,             \
  const float* __restrict__ sim_w, const float* __restrict__ sim_b

// ---- per-pixel sample setup: grid load -> corner coords + weights ----------
#define SAMPLE_SETUP(S, PIX)                                                   \
  const int w##S = (PIX) % WW;                                                 \
  const int t2##S = (PIX) / WW;                                                \
  const int h##S = t2##S & (HH - 1);                                           \
  const int n##S = t2##S >> 8;                                                 \
  const float2 g2##S = *(const float2*)(grid + (size_t)2 *                     \
      (((size_t)((b * NNB + n##S) * HH + h##S)) * WW + w##S));                 \
  float ix##S = fminf(fmaxf(((g2##S.x + 1.0f) * (float)WW - 1.0f) * 0.5f,      \
                            0.0f), (float)(WW - 1));                           \
  float iy##S = fminf(fmaxf(((g2##S.y + 1.0f) * (float)HH - 1.0f) * 0.5f,      \
                            0.0f), (float)(HH - 1));                           \
  float x0f##S = floorf(ix##S), y0f##S = floorf(iy##S);                        \
  float wx##S = ix##S - x0f##S, wy##S = iy##S - y0f##S;                        \
  int x0##S = (int)x0f##S, y0##S = (int)y0f##S;                                \
  int x1##S = min(x0##S + 1, WW - 1), y1##S = min(y0##S + 1, HH - 1);          \
  float w00##S = (1.0f - wx##S) * (1.0f - wy##S);                              \
  float w01##S = wx##S * (1.0f - wy##S);                                       \
  float w10##S = (1.0f - wx##S) * wy##S;                                       \
  float w11##S = wx##S * wy##S;

// ---- per-pixel gathers: 5 streams x 4 uint4 (this half's 32 channels) ------
#define SAMPLE_LOAD(S)                                                         \
  const uint4* p00##S = (const uint4*)(fb + (y0##S * WW + x0##S) * 64);        \
  const uint4* p01##S = (const uint4*)(fb + (y0##S * WW + x1##S) * 64);        \
  const uint4* p10##S = (const uint4*)(fb + (y1##S * WW + x0##S) * 64);        \
  const uint4* p11##S = (const uint4*)(fb + (y1##S * WW + x1##S) * 64);        \
  const uint4* pr##S  = (const uint4*)(fb + (h##S * WW + w##S) * 64);          \
  uint4 A##S[4], B##S[4], C##S[4], D##S[4], R##S[4];                           \
  _Pragma("unroll") for (int k = 0; k < 4; ++k) A##S[k] = p00##S[k];           \
  _Pragma("unroll") for (int k = 0; k < 4; ++k) B##S[k] = p01##S[k];           \
  _Pragma("unroll") for (int k = 0; k < 4; ++k) C##S[k] = p10##S[k];           \
  _Pragma("unroll") for (int k = 0; k < 4; ++k) D##S[k] = p11##S[k];           \
  _Pragma("unroll") for (int k = 0; k < 4; ++k) R##S[k] = pr##S[k];

// ---- per-pixel consume: corr -> half exchange -> MLP -> sigmoid store ------
#define SAMPLE_CONSUME(S, PIX)                                                 \
  {                                                                            \
    float c4[4];                                                               \
    _Pragma("unroll") for (int gg = 0; gg < 4; ++gg) {                         \
      const uint* ua = (const uint*)&A##S[gg];                                 \
      const uint* ub = (const uint*)&B##S[gg];                                 \
      const uint* uc = (const uint*)&C##S[gg];                                 \
      const uint* ud = (const uint*)&D##S[gg];                                 \
      const uint* ur = (const uint*)&R##S[gg];                                 \
      float acc = 0.0f;                                                        \
      _Pragma("unroll") for (int k = 0; k < 4; ++k) {                          \
        float s0 = w00##S * blo(ua[k]) + w01##S * blo(ub[k]) +                 \
                   w10##S * blo(uc[k]) + w11##S * blo(ud[k]);                  \
        acc += s0 * blo(ur[k]);                                                \
        float s1 = w00##S * bhi(ua[k]) + w01##S * bhi(ub[k]) +                 \
                   w10##S * bhi(uc[k]) + w11##S * bhi(ud[k]);                  \
        acc += s1 * bhi(ur[k]);                                                \
      }                                                                        \
      c4[gg] = acc * 0.125f;                                                   \
    }                                                                          \
    float corr[8];                                                             \
    _Pragma("unroll") for (int k = 0; k < 4; ++k) {                            \
      float o = __shfl_xor(c4[k], 32);                                         \
      corr[half * 4 + k] = c4[k];                                              \
      corr[(1 - half) * 4 + k] = o;                                            \
    }                                                                          \
    float h0v[16];                                                             \
    _Pragma("unroll") for (int o = 0; o < 16; ++o) {                           \
      float s = sB0[o];                                                        \
      _Pragma("unroll") for (int g = 0; g < 8; ++g)                            \
          s += sW0[o * 8 + g] * corr[g];                                       \
      h0v[o] = fmaxf(s, 0.0f);                                                 \
    }                                                                          \
    float h1v[8];                                                              \
    _Pragma("unroll") for (int o = 0; o < 8; ++o) {                            \
      float s = sB1[o];                                                        \
      _Pragma("unroll") for (int c = 0; c < 16; ++c)                           \
          s += sW1[o * 16 + c] * h0v[c];                                       \
      h1v[o] = fmaxf(s, 0.0f);                                                 \
    }                                                                          \
    float s = sSB[0];                                                          \
    _Pragma("unroll") for (int c = 0; c < 8; ++c) s += sSW[c] * h1v[c];        \
    if (half == 0)                                                             \
      out[(size_t)b * PIX_PER_B + (PIX)] = 1.0f / (1.0f + __expf(-s));         \
  }

// ---------------------------------------------------------------------------
// Kernel 2 (fast path): 2 lanes per pixel (channel split) x 2 pixels per
// thread. Both pixels' 10 gathers are hoisted and issued back-to-back; px1's
// loads fly under px0's corr+MLP. XCD-pinned batches. Plain launch_bounds:
// the (256,4) hint caused a 64-VGPR target + scratch spill in round 3.
// ---------------------------------------------------------------------------
__global__ __launch_bounds__(256) void fw_main2(
    const ushort* __restrict__ featT, const float* __restrict__ grid,
    WARGS, float* __restrict__ out) {
  FOLD_WEIGHTS();

  // XCD pinning: round-robin dispatch sends block i to XCD i%8.
  // XCDs 0..3 -> batch 0, XCDs 4..7 -> batch 1 (bijective remap).
  // 5760 blocks: j = blk>>3 in [0,720), lblk = j*4+(xcd&3) in [0,2880).
  const int blk = blockIdx.x;
  const int xcd = blk & 7;
  const int j = blk >> 3;
  const int b = xcd >> 2;
  const int lblk = j * 4 + (xcd & 3);

  const int tid = threadIdx.x;
  const int lane = tid & 63;
  const int wid = tid >> 6;                // wave in block, 0..3
  const int half = lane >> 5;              // 0: groups 0..3, 1: groups 4..7
  const int pix0 = lblk * PIX_PER_BLOCK + wid * 64 + (lane & 31);  // [0,737280)
  const int pix1 = pix0 + 32;

  const ushort* fb = featT + (size_t)b * (HH * WW * 64) + half * 32;

  // setup + issue ALL gathers for both pixels before any consume
  SAMPLE_SETUP(a, pix0)
  SAMPLE_SETUP(bq, pix1)
  SAMPLE_LOAD(a)
  SAMPLE_LOAD(bq)

  SAMPLE_CONSUME(a, pix0)
  SAMPLE_CONSUME(bq, pix1)
}

// ---------------------------------------------------------------------------
// Fallback (no workspace): 1 thread per pixel, direct fp32 gathers.
// ---------------------------------------------------------------------------
__global__ __launch_bounds__(256) void fw_main_fallback(
    const float* __restrict__ feat, const float* __restrict__ grid,
    WARGS, float* __restrict__ out) {
  FOLD_WEIGHTS();
  const int t = blockIdx.x * 256 + threadIdx.x;
  const int w = t % WW;
  const int tmp = t / WW;
  const int h = tmp & (HH - 1);
  const int nb = tmp >> 8;
  const int n = nb % NNB;
  const int b = nb / NNB;

  const float2 g2 =
      *(const float2*)(grid + (size_t)2 * (((size_t)((b * NNB + n) * HH + h)) * WW + w));
  float ix = fminf(fmaxf(((g2.x + 1.0f) * (float)WW - 1.0f) * 0.5f, 0.0f), (float)(WW - 1));
  float iy = fminf(fmaxf(((g2.y + 1.0f) * (float)HH - 1.0f) * 0.5f, 0.0f), (float)(HH - 1));
  float x0f = floorf(ix), y0f = floorf(iy);
  float wx = ix - x0f, wy = iy - y0f;
  int x0 = (int)x0f, y0 = (int)y0f;
  int x1 = min(x0 + 1, WW - 1), y1 = min(y0 + 1, HH - 1);
  float w00 = (1.0f - wx) * (1.0f - wy), w01 = wx * (1.0f - wy);
  float w10 = (1.0f - wx) * wy, w11 = wx * wy;

  float corr[8];
  const float* fbp = feat + (size_t)b * (CC * HH * WW);
#pragma unroll
  for (int g = 0; g < 8; ++g) {
    float acc = 0.0f;
    for (int ch = 0; ch < 8; ++ch) {
      const float* fc = fbp + (size_t)(g * 8 + ch) * (HH * WW);
      float sv = w00 * fc[y0 * WW + x0] + w01 * fc[y0 * WW + x1] +
                 w10 * fc[y1 * WW + x0] + w11 * fc[y1 * WW + x1];
      acc += sv * fc[h * WW + w];
    }
    corr[g] = acc * 0.125f;
  }

  float h0v[16];
#pragma unroll
  for (int o = 0; o < 16; ++o) {
    float s = sB0[o];
#pragma unroll
    for (int g = 0; g < 8; ++g) s += sW0[o * 8 + g] * corr[g];
    h0v[o] = fmaxf(s, 0.0f);
  }
  float h1v[8];
#pragma unroll
  for (int o = 0; o < 8; ++o) {
    float s = sB1[o];
#pragma unroll
    for (int c = 0; c < 16; ++c) s += sW1[o * 16 + c] * h0v[c];
    h1v[o] = fmaxf(s, 0.0f);
  }
  float s = sSB[0];
#pragma unroll
  for (int c = 0; c < 8; ++c) s += sSW[c] * h1v[c];
  out[t] = 1.0f / (1.0f + __expf(-s));
}

// ---------------------------------------------------------------------------
extern "C" void kernel_launch(void* const* d_in, const int* in_sizes, int n_in,
                              void* d_out, int out_size, void* d_ws, size_t ws_size,
                              hipStream_t stream) {
  const float* ref_feature = (const float*)d_in[0];
  const float* grid    = (const float*)d_in[1];
  const float* conv0_w = (const float*)d_in[2];
  const float* bn0_g   = (const float*)d_in[3];
  const float* bn0_b   = (const float*)d_in[4];
  const float* bn0_m   = (const float*)d_in[5];
  const float* bn0_v   = (const float*)d_in[6];
  const float* conv1_w = (const float*)d_in[7];
  const float* bn1_g   = (const float*)d_in[8];
  const float* bn1_b   = (const float*)d_in[9];
  const float* bn1_m   = (const float*)d_in[10];
  const float* bn1_v   = (const float*)d_in[11];
  const float* sim_w   = (const float*)d_in[12];
  const float* sim_b   = (const float*)d_in[13];
  float* out = (float*)d_out;

  const size_t needT = (size_t)BB * HH * WW * 64 * sizeof(ushort);  // ~21 MB

  if (ws_size >= needT) {
    ushort* featT = (ushort*)d_ws;
    fw_transpose<<<dim3(WW / 64, HH, BB), 256, 0, stream>>>(ref_feature, featT);
    // 256 pixels per block (256 threads, 2 lanes/pixel, 2 px/thread):
    // 1,474,560 / 256 = 5,760 blocks.
    const int blocks2 = BB * PIX_PER_B / PIX_PER_BLOCK;
    fw_main2<<<blocks2, 256, 0, stream>>>(featT, grid,
        conv0_w, bn0_g, bn0_b, bn0_m, bn0_v,
        conv1_w, bn1_g, bn1_b, bn1_m, bn1_v, sim_w, sim_b, out);
  } else {
    fw_main_fallback<<<BB * PIX_PER_B / 256, 256, 0, stream>>>(ref_feature, grid,
        conv0_w, bn0_g, bn0_b, bn0_m, bn0_v,
        conv1_w, bn1_g, bn1_b, bn1_m, bn1_v, sim_w, sim_b, out);
  }
}

// Round 6
// 143.186 us; speedup vs baseline: 1.0414x; 1.0414x over previous
//
#include <hip/hip_runtime.h>
#include <hip/hip_bf16.h>

#define BB  2
#define CC  64
#define HH  256
#define WW  320
#define NNB 9
#define PIX_PER_B (NNB * HH * WW)   // 737280

typedef unsigned int uint;

// ws layout: [0, 20971520) bf16 featT ; [20971520, +1216) folded weights
#define FEATT_BYTES ((size_t)BB * HH * WW * 64 * sizeof(ushort))
#define NWTS 304                     // 289 used, padded

// folded-weight table offsets (floats)
#define OW0 0      // [16][8]
#define OB0 128    // [16]
#define OW1 144    // [8][16]
#define OB1 272    // [8]
#define OSW 280    // [8]
#define OSB 288    // [1]

// ---------------------------------------------------------------------------
// Kernel 0: fold BN into affine weights, once, into ws (global).
// ---------------------------------------------------------------------------
__global__ __launch_bounds__(64) void fw_fold(
    const float* __restrict__ conv0_w, const float* __restrict__ bn0_g,
    const float* __restrict__ bn0_b, const float* __restrict__ bn0_m,
    const float* __restrict__ bn0_v, const float* __restrict__ conv1_w,
    const float* __restrict__ bn1_g, const float* __restrict__ bn1_b,
    const float* __restrict__ bn1_m, const float* __restrict__ bn1_v,
    const float* __restrict__ sim_w, const float* __restrict__ sim_b,
    float* __restrict__ wts) {
  const int t = threadIdx.x;
  if (t < 16) {
    float a = bn0_g[t] * rsqrtf(bn0_v[t] + 1e-5f);
    wts[OB0 + t] = bn0_b[t] - bn0_m[t] * a;
#pragma unroll
    for (int g = 0; g < 8; ++g) wts[OW0 + t * 8 + g] = conv0_w[t * 8 + g] * a;
  } else if (t < 24) {
    int o = t - 16;
    float a = bn1_g[o] * rsqrtf(bn1_v[o] + 1e-5f);
    wts[OB1 + o] = bn1_b[o] - bn1_m[o] * a;
#pragma unroll
    for (int c = 0; c < 16; ++c) wts[OW1 + o * 16 + c] = conv1_w[o * 16 + c] * a;
  } else if (t < 32) {
    wts[OSW + t - 24] = sim_w[t - 24];
    if (t == 31) wts[OSB] = sim_b[0];
  }
}

// ---------------------------------------------------------------------------
// Kernel 1: transpose [B,C,H,W] fp32 -> [B,H,W,C] bf16 (channel-contiguous)
// ---------------------------------------------------------------------------
__global__ __launch_bounds__(256) void fw_transpose(const float* __restrict__ feat,
                                                    ushort* __restrict__ featT) {
  __shared__ float tile[64][65];
  const int b = blockIdx.z, h = blockIdx.y, w0 = blockIdx.x * 64;
  const int tid = threadIdx.x;
#pragma unroll
  for (int it = 0; it < 16; ++it) {
    int idx = it * 256 + tid;
    int c = idx >> 6, w = idx & 63;
    tile[c][w] = feat[((b * CC + c) * HH + h) * WW + w0 + w];
  }
  __syncthreads();
#pragma unroll
  for (int it = 0; it < 16; ++it) {
    int idx = it * 256 + tid;
    int w = idx >> 6, c = idx & 63;
    __hip_bfloat16 v = __float2bfloat16(tile[c][w]);
    featT[((b * HH + h) * WW + w0 + w) * 64 + c] = *(ushort*)&v;
  }
}

__device__ __forceinline__ float blo(uint u) { return __uint_as_float(u << 16); }
__device__ __forceinline__ float bhi(uint u) { return __uint_as_float(u & 0xffff0000u); }

// ---------------------------------------------------------------------------
// Kernel 2 (fast path): 2 lanes per pixel (channel split), 5 hoisted 64B
// gathers, XCD-pinned batches. Weights come from the pre-folded global table
// via wave-uniform constant-index reads -> scalar loads (no LDS, no barrier,
// no per-FMA ds_read). 512-thread blocks (zero LDS -> VGPR-only occupancy).
// ---------------------------------------------------------------------------
__global__ __launch_bounds__(512) void fw_main2(
    const ushort* __restrict__ featT, const float* __restrict__ grid,
    const float* __restrict__ wts, float* __restrict__ out) {
  // XCD pinning: round-robin dispatch sends block i to XCD i%8.
  // XCDs 0..3 -> batch 0, XCDs 4..7 -> batch 1 (bijective remap).
  // 5760 blocks: j = blk>>3 in [0,720), lblk = j*4+(xcd&3) in [0,2880).
  const int blk = blockIdx.x;
  const int xcd = blk & 7;
  const int j = blk >> 3;
  const int b = xcd >> 2;
  const int lblk = j * 4 + (xcd & 3);

  const int tid = threadIdx.x;
  const int lane = tid & 63;
  const int wid = tid >> 6;                // wave in block, 0..7
  const int half = lane >> 5;              // 0: groups 0..3, 1: groups 4..7
  const int pix = lblk * 256 + wid * 32 + (lane & 31);  // [0, 737280)

  const int w = pix % WW;
  const int t2 = pix / WW;
  const int h = t2 & (HH - 1);
  const int n = t2 >> 8;                   // 0..8

  // ---- grid -> bilinear corners (border padding, align_corners=False) ----
  const float2 g2 =
      *(const float2*)(grid + (size_t)2 * (((size_t)((b * NNB + n) * HH + h)) * WW + w));
  float ix = fminf(fmaxf(((g2.x + 1.0f) * (float)WW - 1.0f) * 0.5f, 0.0f), (float)(WW - 1));
  float iy = fminf(fmaxf(((g2.y + 1.0f) * (float)HH - 1.0f) * 0.5f, 0.0f), (float)(HH - 1));
  float x0f = floorf(ix), y0f = floorf(iy);
  float wx = ix - x0f, wy = iy - y0f;
  int x0 = (int)x0f, y0 = (int)y0f;
  int x1 = min(x0 + 1, WW - 1), y1 = min(y0 + 1, HH - 1);
  float w00 = (1.0f - wx) * (1.0f - wy);
  float w01 = wx * (1.0f - wy);
  float w10 = (1.0f - wx) * wy;
  float w11 = wx * wy;

  // ---- hoisted gathers: 5 streams x 4 uint4 (this half's 32 channels) ----
  const ushort* fb = featT + (size_t)b * (HH * WW * 64) + half * 32;
  const uint4* p00 = (const uint4*)(fb + (y0 * WW + x0) * 64);
  const uint4* p01 = (const uint4*)(fb + (y0 * WW + x1) * 64);
  const uint4* p10 = (const uint4*)(fb + (y1 * WW + x0) * 64);
  const uint4* p11 = (const uint4*)(fb + (y1 * WW + x1) * 64);
  const uint4* pr  = (const uint4*)(fb + (h * WW + w) * 64);

  uint4 A[4], Bv[4], Cv[4], Dv[4], Rv[4];
#pragma unroll
  for (int k = 0; k < 4; ++k) A[k] = p00[k];
#pragma unroll
  for (int k = 0; k < 4; ++k) Bv[k] = p01[k];
#pragma unroll
  for (int k = 0; k < 4; ++k) Cv[k] = p10[k];
#pragma unroll
  for (int k = 0; k < 4; ++k) Dv[k] = p11[k];
#pragma unroll
  for (int k = 0; k < 4; ++k) Rv[k] = pr[k];

  // ---- 4 local group correlations ----------------------------------------
  float c4[4];
#pragma unroll
  for (int gg = 0; gg < 4; ++gg) {
    const uint* ua = (const uint*)&A[gg];
    const uint* ub = (const uint*)&Bv[gg];
    const uint* uc = (const uint*)&Cv[gg];
    const uint* ud = (const uint*)&Dv[gg];
    const uint* ur = (const uint*)&Rv[gg];
    float acc = 0.0f;
#pragma unroll
    for (int k = 0; k < 4; ++k) {
      float s0 = w00 * blo(ua[k]) + w01 * blo(ub[k]) + w10 * blo(uc[k]) + w11 * blo(ud[k]);
      acc += s0 * blo(ur[k]);
      float s1 = w00 * bhi(ua[k]) + w01 * bhi(ub[k]) + w10 * bhi(uc[k]) + w11 * bhi(ud[k]);
      acc += s1 * bhi(ur[k]);
    }
    c4[gg] = acc * 0.125f;
  }

  // ---- exchange the other half's 4 correlations --------------------------
  float corr[8];
#pragma unroll
  for (int k = 0; k < 4; ++k) {
    float o = __shfl_xor(c4[k], 32);
    corr[half * 4 + k] = c4[k];
    corr[(1 - half) * 4 + k] = o;
  }

  // ---- tiny MLP (weights: wave-uniform scalar loads) + sigmoid -----------
  float h0v[16];
#pragma unroll
  for (int o = 0; o < 16; ++o) {
    float s = wts[OB0 + o];
#pragma unroll
    for (int g = 0; g < 8; ++g) s += wts[OW0 + o * 8 + g] * corr[g];
    h0v[o] = fmaxf(s, 0.0f);
  }
  float h1v[8];
#pragma unroll
  for (int o = 0; o < 8; ++o) {
    float s = wts[OB1 + o];
#pragma unroll
    for (int c = 0; c < 16; ++c) s += wts[OW1 + o * 16 + c] * h0v[c];
    h1v[o] = fmaxf(s, 0.0f);
  }
  float s = wts[OSB];
#pragma unroll
  for (int c = 0; c < 8; ++c) s += wts[OSW + c] * h1v[c];

  if (half == 0) out[(size_t)b * PIX_PER_B + pix] = 1.0f / (1.0f + __expf(-s));
}

// ---------------------------------------------------------------------------
// Fallback (no workspace): 1 thread per pixel, direct fp32 gathers,
// per-block LDS weight fold (original round-1 path).
// ---------------------------------------------------------------------------
__global__ __launch_bounds__(256) void fw_main_fallback(
    const float* __restrict__ feat, const float* __restrict__ grid,
    const float* __restrict__ conv0_w, const float* __restrict__ bn0_g,
    const float* __restrict__ bn0_b, const float* __restrict__ bn0_m,
    const float* __restrict__ bn0_v, const float* __restrict__ conv1_w,
    const float* __restrict__ bn1_g, const float* __restrict__ bn1_b,
    const float* __restrict__ bn1_m, const float* __restrict__ bn1_v,
    const float* __restrict__ sim_w, const float* __restrict__ sim_b,
    float* __restrict__ out) {
  __shared__ float sW0[16 * 8], sB0[16], sW1[8 * 16], sB1[8], sSW[8], sSB[1];
  {
    const int tt = threadIdx.x;
    if (tt < 16) {
      float a = bn0_g[tt] * rsqrtf(bn0_v[tt] + 1e-5f);
      sB0[tt] = bn0_b[tt] - bn0_m[tt] * a;
#pragma unroll
      for (int g = 0; g < 8; ++g) sW0[tt * 8 + g] = conv0_w[tt * 8 + g] * a;
    } else if (tt < 24) {
      int o = tt - 16;
      float a = bn1_g[o] * rsqrtf(bn1_v[o] + 1e-5f);
      sB1[o] = bn1_b[o] - bn1_m[o] * a;
#pragma unroll
      for (int c = 0; c < 16; ++c) sW1[o * 16 + c] = conv1_w[o * 16 + c] * a;
    } else if (tt < 32) {
      sSW[tt - 24] = sim_w[tt - 24];
      if (tt == 31) sSB[0] = sim_b[0];
    }
  }
  __syncthreads();

  const int t = blockIdx.x * 256 + threadIdx.x;
  const int w = t % WW;
  const int tmp = t / WW;
  const int h = tmp & (HH - 1);
  const int nb = tmp >> 8;
  const int n = nb % NNB;
  const int b = nb / NNB;

  const float2 g2 =
      *(const float2*)(grid + (size_t)2 * (((size_t)((b * NNB + n) * HH + h)) * WW + w));
  float ix = fminf(fmaxf(((g2.x + 1.0f) * (float)WW - 1.0f) * 0.5f, 0.0f), (float)(WW - 1));
  float iy = fminf(fmaxf(((g2.y + 1.0f) * (float)HH - 1.0f) * 0.5f, 0.0f), (float)(HH - 1));
  float x0f = floorf(ix), y0f = floorf(iy);
  float wx = ix - x0f, wy = iy - y0f;
  int x0 = (int)x0f, y0 = (int)y0f;
  int x1 = min(x0 + 1, WW - 1), y1 = min(y0 + 1, HH - 1);
  float w00 = (1.0f - wx) * (1.0f - wy), w01 = wx * (1.0f - wy);
  float w10 = (1.0f - wx) * wy, w11 = wx * wy;

  float corr[8];
  const float* fbp = feat + (size_t)b * (CC * HH * WW);
#pragma unroll
  for (int g = 0; g < 8; ++g) {
    float acc = 0.0f;
    for (int ch = 0; ch < 8; ++ch) {
      const float* fc = fbp + (size_t)(g * 8 + ch) * (HH * WW);
      float sv = w00 * fc[y0 * WW + x0] + w01 * fc[y0 * WW + x1] +
                 w10 * fc[y1 * WW + x0] + w11 * fc[y1 * WW + x1];
      acc += sv * fc[h * WW + w];
    }
    corr[g] = acc * 0.125f;
  }

  float h0v[16];
#pragma unroll
  for (int o = 0; o < 16; ++o) {
    float s = sB0[o];
#pragma unroll
    for (int g = 0; g < 8; ++g) s += sW0[o * 8 + g] * corr[g];
    h0v[o] = fmaxf(s, 0.0f);
  }
  float h1v[8];
#pragma unroll
  for (int o = 0; o < 8; ++o) {
    float s = sB1[o];
#pragma unroll
    for (int c = 0; c < 16; ++c) s += sW1[o * 16 + c] * h0v[c];
    h1v[o] = fmaxf(s, 0.0f);
  }
  float s = sSB[0];
#pragma unroll
  for (int c = 0; c < 8; ++c) s += sSW[c] * h1v[c];
  out[t] = 1.0f / (1.0f + __expf(-s));
}

// ---------------------------------------------------------------------------
extern "C" void kernel_launch(void* const* d_in, const int* in_sizes, int n_in,
                              void* d_out, int out_size, void* d_ws, size_t ws_size,
                              hipStream_t stream) {
  const float* ref_feature = (const float*)d_in[0];
  const float* grid    = (const float*)d_in[1];
  const float* conv0_w = (const float*)d_in[2];
  const float* bn0_g   = (const float*)d_in[3];
  const float* bn0_b   = (const float*)d_in[4];
  const float* bn0_m   = (const float*)d_in[5];
  const float* bn0_v   = (const float*)d_in[6];
  const float* conv1_w = (const float*)d_in[7];
  const float* bn1_g   = (const float*)d_in[8];
  const float* bn1_b   = (const float*)d_in[9];
  const float* bn1_m   = (const float*)d_in[10];
  const float* bn1_v   = (const float*)d_in[11];
  const float* sim_w   = (const float*)d_in[12];
  const float* sim_b   = (const float*)d_in[13];
  float* out = (float*)d_out;

  const size_t need = FEATT_BYTES + NWTS * sizeof(float);

  if (ws_size >= need) {
    ushort* featT = (ushort*)d_ws;
    float* wts = (float*)((char*)d_ws + FEATT_BYTES);
    fw_fold<<<1, 64, 0, stream>>>(conv0_w, bn0_g, bn0_b, bn0_m, bn0_v,
                                  conv1_w, bn1_g, bn1_b, bn1_m, bn1_v,
                                  sim_w, sim_b, wts);
    fw_transpose<<<dim3(WW / 64, HH, BB), 256, 0, stream>>>(ref_feature, featT);
    // 512 threads = 256 pixels per block (2 lanes/pixel):
    // 1,474,560 / 256 = 5,760 blocks.
    fw_main2<<<BB * PIX_PER_B / 256, 512, 0, stream>>>(featT, grid, wts, out);
  } else {
    fw_main_fallback<<<BB * PIX_PER_B / 256, 256, 0, stream>>>(ref_feature, grid,
        conv0_w, bn0_g, bn0_b, bn0_m, bn0_v,
        conv1_w, bn1_g, bn1_b, bn1_m, bn1_v, sim_w, sim_b, out);
  }
}

// Round 7
// 103.085 us; speedup vs baseline: 1.4466x; 1.3890x over previous
//
#include <hip/hip_runtime.h>
#include <hip/hip_bf16.h>

#define BB  2
#define CC  64
#define HH  256
#define WW  320
#define NNB 9
#define PIX_PER_B (NNB * HH * WW)   // 737280
#define HW (HH * WW)                // 81920

typedef unsigned int uint;

// ws layout: [0, FEATT_BYTES) bf16 featT ; then folded weights
#define FEATT_BYTES ((size_t)BB * HH * WW * 64 * sizeof(ushort))
#define NWTS 304

// folded-weight table offsets (floats)
#define OW0 0      // [16][8]
#define OB0 128    // [16]
#define OW1 144    // [8][16]
#define OB1 272    // [8]
#define OSW 280    // [8]
#define OSB 288    // [1]

// ---------------------------------------------------------------------------
// Kernel 0: fold BN into affine weights, once, into ws (global).
// ---------------------------------------------------------------------------
__global__ __launch_bounds__(64) void fw_fold(
    const float* __restrict__ conv0_w, const float* __restrict__ bn0_g,
    const float* __restrict__ bn0_b, const float* __restrict__ bn0_m,
    const float* __restrict__ bn0_v, const float* __restrict__ conv1_w,
    const float* __restrict__ bn1_g, const float* __restrict__ bn1_b,
    const float* __restrict__ bn1_m, const float* __restrict__ bn1_v,
    const float* __restrict__ sim_w, const float* __restrict__ sim_b,
    float* __restrict__ wts) {
  const int t = threadIdx.x;
  if (t < 16) {
    float a = bn0_g[t] * rsqrtf(bn0_v[t] + 1e-5f);
    wts[OB0 + t] = bn0_b[t] - bn0_m[t] * a;
#pragma unroll
    for (int g = 0; g < 8; ++g) wts[OW0 + t * 8 + g] = conv0_w[t * 8 + g] * a;
  } else if (t < 24) {
    int o = t - 16;
    float a = bn1_g[o] * rsqrtf(bn1_v[o] + 1e-5f);
    wts[OB1 + o] = bn1_b[o] - bn1_m[o] * a;
#pragma unroll
    for (int c = 0; c < 16; ++c) wts[OW1 + o * 16 + c] = conv1_w[o * 16 + c] * a;
  } else if (t < 32) {
    wts[OSW + t - 24] = sim_w[t - 24];
    if (t == 31) wts[OSB] = sim_b[0];
  }
}

// ---------------------------------------------------------------------------
// Kernel 1: transpose [B,C,H,W] fp32 -> [B,H,W,C] bf16 (channel-contiguous)
// ---------------------------------------------------------------------------
__global__ __launch_bounds__(256) void fw_transpose(const float* __restrict__ feat,
                                                    ushort* __restrict__ featT) {
  __shared__ float tile[64][65];
  const int b = blockIdx.z, h = blockIdx.y, w0 = blockIdx.x * 64;
  const int tid = threadIdx.x;
#pragma unroll
  for (int it = 0; it < 16; ++it) {
    int idx = it * 256 + tid;
    int c = idx >> 6, w = idx & 63;
    tile[c][w] = feat[((b * CC + c) * HH + h) * WW + w0 + w];
  }
  __syncthreads();
#pragma unroll
  for (int it = 0; it < 16; ++it) {
    int idx = it * 256 + tid;
    int w = idx >> 6, c = idx & 63;
    __hip_bfloat16 v = __float2bfloat16(tile[c][w]);
    featT[((b * HH + h) * WW + w0 + w) * 64 + c] = *(ushort*)&v;
  }
}

__device__ __forceinline__ float blo(uint u) { return __uint_as_float(u << 16); }
__device__ __forceinline__ float bhi(uint u) { return __uint_as_float(u & 0xffff0000u); }

// ---------------------------------------------------------------------------
// Kernel 2: 8 lanes per pixel. Lane j of a team loads channels 8j..8j+8
// (= group j) of each bilinear corner as ONE 16B load inside a 128B-
// contiguous 8-lane cluster -> 5 line-transactions per pixel (min possible).
// 8 stages x 8 teams = 64 pixels/wave, 2-deep software pipeline, then an
// 8x8 butterfly register transpose gives each lane one pixel's corr[8] and
// the MLP runs once per pixel. Weights via wave-uniform scalar loads.
// ---------------------------------------------------------------------------
__global__ __launch_bounds__(256) void fw_main3(
    const ushort* __restrict__ featT, const float* __restrict__ grid,
    const float* __restrict__ wts, float* __restrict__ out) {
  // XCD pinning (round-robin dispatch: block i -> XCD i%8).
  // XCDs 0..3 -> batch 0, XCDs 4..7 -> batch 1. 5760 blocks.
  const int blk = blockIdx.x;
  const int xcd = blk & 7;
  const int jb = blk >> 3;                  // 0..720
  const int b = xcd >> 2;
  const int lblk = jb * 4 + (xcd & 3);      // 0..2880

  const int tid = threadIdx.x;
  const int lane = tid & 63;
  const int wid = tid >> 6;                 // wave in block, 0..3
  const int team = lane >> 3;               // 0..7
  const int lj = lane & 7;                  // lane-in-team = channel group
  const int wbase = lblk * 256 + wid * 64;  // wave's first pixel (in batch)

  const ushort* __restrict__ fbT = featT + (size_t)b * ((size_t)HW * 64);

  // ---- owner-lane setup: pixel (wbase + lane) ----------------------------
  float wx, wy;
  int off00, offc;
  {
    const int pix = wbase + lane;
    const float2 g2 =
        *(const float2*)(grid + (size_t)2 * ((size_t)b * PIX_PER_B + pix));
    float ix = fminf(fmaxf(((g2.x + 1.0f) * (float)WW - 1.0f) * 0.5f, 0.0f),
                     (float)(WW - 1));
    float iy = fminf(fmaxf(((g2.y + 1.0f) * (float)HH - 1.0f) * 0.5f, 0.0f),
                     (float)(HH - 1));
    // x0=min(floor,W-2), wx=ix-x0 is exactly the reference's clamped bilinear
    // (at ix=W-1: wx=1 so the x0 corner has weight 0); guarantees x1=x0+1
    // in-bounds -> corner pairs are 256B contiguous, no OOB.
    int x0 = min((int)floorf(ix), WW - 2);
    int y0 = min((int)floorf(iy), HH - 2);
    wx = ix - (float)x0;
    wy = iy - (float)y0;
    off00 = (y0 * WW + x0) * 64;            // element offset of corner(y0,x0)
    offc = (pix % HW) * 64;                 // element offset of center (h,w)
  }

  float pc[8];   // pc[s] = group-lj corr partial of pixel s*8+team

  // ---- per-stage macros ---------------------------------------------------
#define PERM(S, PX, PY, PO, PQ)                                                \
  {                                                                            \
    int src = (S)*8 + team;                                                    \
    PX = __shfl(wx, src);                                                      \
    PY = __shfl(wy, src);                                                      \
    PO = __shfl(off00, src);                                                   \
    PQ = __shfl(offc, src);                                                    \
  }

#define LOADS(PO, PQ, L0, L1, L2, L3, L4)                                      \
  {                                                                            \
    const ushort* base = fbT + PO + lj * 8;                                    \
    L0 = *(const uint4*)(base);              /* c00 */                         \
    L1 = *(const uint4*)(base + 64);         /* c01 */                         \
    L2 = *(const uint4*)(base + WW * 64);    /* c10 */                         \
    L3 = *(const uint4*)(base + WW * 64 + 64); /* c11 */                       \
    L4 = *(const uint4*)(fbT + PQ + lj * 8); /* center */                      \
  }

#define CORRS(S, PX, PY, L0, L1, L2, L3, L4)                                   \
  {                                                                            \
    float e00 = (1.0f - PX) * (1.0f - PY);                                     \
    float e01 = PX * (1.0f - PY);                                              \
    float e10 = (1.0f - PX) * PY;                                              \
    float e11 = PX * PY;                                                       \
    const uint* ua = (const uint*)&L0;                                         \
    const uint* ub = (const uint*)&L1;                                         \
    const uint* uc = (const uint*)&L2;                                         \
    const uint* ud = (const uint*)&L3;                                         \
    const uint* ur = (const uint*)&L4;                                         \
    float acc = 0.0f;                                                          \
    _Pragma("unroll") for (int k = 0; k < 4; ++k) {                            \
      float s0 = e00 * blo(ua[k]) + e01 * blo(ub[k]) + e10 * blo(uc[k]) +      \
                 e11 * blo(ud[k]);                                             \
      acc += s0 * blo(ur[k]);                                                  \
      float s1 = e00 * bhi(ua[k]) + e01 * bhi(ub[k]) + e10 * bhi(uc[k]) +      \
                 e11 * bhi(ud[k]);                                             \
      acc += s1 * bhi(ur[k]);                                                  \
    }                                                                          \
    pc[S] = acc * 0.125f;                                                      \
  }

  float pxA, pyA, pxB, pyB;
  int poA, pqA, poB, pqB;
  uint4 A0, A1, A2, A3, A4, B0, B1, B2, B3, B4;

  // 2-deep pipeline over 8 stages
  PERM(0, pxA, pyA, poA, pqA) LOADS(poA, pqA, A0, A1, A2, A3, A4)
  PERM(1, pxB, pyB, poB, pqB) LOADS(poB, pqB, B0, B1, B2, B3, B4)
  CORRS(0, pxA, pyA, A0, A1, A2, A3, A4)
  PERM(2, pxA, pyA, poA, pqA) LOADS(poA, pqA, A0, A1, A2, A3, A4)
  CORRS(1, pxB, pyB, B0, B1, B2, B3, B4)
  PERM(3, pxB, pyB, poB, pqB) LOADS(poB, pqB, B0, B1, B2, B3, B4)
  CORRS(2, pxA, pyA, A0, A1, A2, A3, A4)
  PERM(4, pxA, pyA, poA, pqA) LOADS(poA, pqA, A0, A1, A2, A3, A4)
  CORRS(3, pxB, pyB, B0, B1, B2, B3, B4)
  PERM(5, pxB, pyB, poB, pqB) LOADS(poB, pqB, B0, B1, B2, B3, B4)
  CORRS(4, pxA, pyA, A0, A1, A2, A3, A4)
  PERM(6, pxA, pyA, poA, pqA) LOADS(poA, pqA, A0, A1, A2, A3, A4)
  CORRS(5, pxB, pyB, B0, B1, B2, B3, B4)
  PERM(7, pxB, pyB, poB, pqB) LOADS(poB, pqB, B0, B1, B2, B3, B4)
  CORRS(6, pxA, pyA, A0, A1, A2, A3, A4)
  CORRS(7, pxB, pyB, B0, B1, B2, B3, B4)

#undef PERM
#undef LOADS
#undef CORRS

  // ---- 8x8 butterfly register transpose (within each 8-lane team) --------
  // pre:  lane(team,lj) slot s = group lj of pixel s*8+team
  // post: lane(team,lj) slot g = group g  of pixel lj*8+team
#pragma unroll
  for (int m = 1; m < 8; m <<= 1) {
    float tmp[8];
#pragma unroll
    for (int s = 0; s < 8; ++s) tmp[s] = pc[s];
#pragma unroll
    for (int s = 0; s < 8; ++s) {
      float r = __shfl_xor(tmp[s ^ m], m);
      pc[s] = (((lj & m) != 0) == ((s & m) != 0)) ? tmp[s] : r;
    }
  }

  // ---- MLP (weights: wave-uniform scalar loads) + sigmoid ----------------
  float h0v[16];
#pragma unroll
  for (int o = 0; o < 16; ++o) {
    float s = wts[OB0 + o];
#pragma unroll
    for (int g = 0; g < 8; ++g) s += wts[OW0 + o * 8 + g] * pc[g];
    h0v[o] = fmaxf(s, 0.0f);
  }
  float h1v[8];
#pragma unroll
  for (int o = 0; o < 8; ++o) {
    float s = wts[OB1 + o];
#pragma unroll
    for (int c = 0; c < 16; ++c) s += wts[OW1 + o * 16 + c] * h0v[c];
    h1v[o] = fmaxf(s, 0.0f);
  }
  float s = wts[OSB];
#pragma unroll
  for (int c = 0; c < 8; ++c) s += wts[OSW + c] * h1v[c];

  out[(size_t)b * PIX_PER_B + wbase + lj * 8 + team] =
      1.0f / (1.0f + __expf(-s));
}

// ---------------------------------------------------------------------------
// Fallback (no workspace): 1 thread per pixel, direct fp32 gathers,
// per-block LDS weight fold.
// ---------------------------------------------------------------------------
__global__ __launch_bounds__(256) void fw_main_fallback(
    const float* __restrict__ feat, const float* __restrict__ grid,
    const float* __restrict__ conv0_w, const float* __restrict__ bn0_g,
    const float* __restrict__ bn0_b, const float* __restrict__ bn0_m,
    const float* __restrict__ bn0_v, const float* __restrict__ conv1_w,
    const float* __restrict__ bn1_g, const float* __restrict__ bn1_b,
    const float* __restrict__ bn1_m, const float* __restrict__ bn1_v,
    const float* __restrict__ sim_w, const float* __restrict__ sim_b,
    float* __restrict__ out) {
  __shared__ float sW0[16 * 8], sB0[16], sW1[8 * 16], sB1[8], sSW[8], sSB[1];
  {
    const int tt = threadIdx.x;
    if (tt < 16) {
      float a = bn0_g[tt] * rsqrtf(bn0_v[tt] + 1e-5f);
      sB0[tt] = bn0_b[tt] - bn0_m[tt] * a;
#pragma unroll
      for (int g = 0; g < 8; ++g) sW0[tt * 8 + g] = conv0_w[tt * 8 + g] * a;
    } else if (tt < 24) {
      int o = tt - 16;
      float a = bn1_g[o] * rsqrtf(bn1_v[o] + 1e-5f);
      sB1[o] = bn1_b[o] - bn1_m[o] * a;
#pragma unroll
      for (int c = 0; c < 16; ++c) sW1[o * 16 + c] = conv1_w[o * 16 + c] * a;
    } else if (tt < 32) {
      sSW[tt - 24] = sim_w[tt - 24];
      if (tt == 31) sSB[0] = sim_b[0];
    }
  }
  __syncthreads();

  const int t = blockIdx.x * 256 + threadIdx.x;
  const int w = t % WW;
  const int tmp = t / WW;
  const int h = tmp & (HH - 1);
  const int nb = tmp >> 8;
  const int n = nb % NNB;
  const int b = nb / NNB;

  const float2 g2 =
      *(const float2*)(grid + (size_t)2 * (((size_t)((b * NNB + n) * HH + h)) * WW + w));
  float ix = fminf(fmaxf(((g2.x + 1.0f) * (float)WW - 1.0f) * 0.5f, 0.0f), (float)(WW - 1));
  float iy = fminf(fmaxf(((g2.y + 1.0f) * (float)HH - 1.0f) * 0.5f, 0.0f), (float)(HH - 1));
  float x0f = floorf(ix), y0f = floorf(iy);
  float wx = ix - x0f, wy = iy - y0f;
  int x0 = (int)x0f, y0 = (int)y0f;
  int x1 = min(x0 + 1, WW - 1), y1 = min(y0 + 1, HH - 1);
  float w00 = (1.0f - wx) * (1.0f - wy), w01 = wx * (1.0f - wy);
  float w10 = (1.0f - wx) * wy, w11 = wx * wy;

  float corr[8];
  const float* fbp = feat + (size_t)b * (CC * HH * WW);
#pragma unroll
  for (int g = 0; g < 8; ++g) {
    float acc = 0.0f;
    for (int ch = 0; ch < 8; ++ch) {
      const float* fc = fbp + (size_t)(g * 8 + ch) * (HH * WW);
      float sv = w00 * fc[y0 * WW + x0] + w01 * fc[y0 * WW + x1] +
                 w10 * fc[y1 * WW + x0] + w11 * fc[y1 * WW + x1];
      acc += sv * fc[h * WW + w];
    }
    corr[g] = acc * 0.125f;
  }

  float h0v[16];
#pragma unroll
  for (int o = 0; o < 16; ++o) {
    float s = sB0[o];
#pragma unroll
    for (int g = 0; g < 8; ++g) s += sW0[o * 8 + g] * corr[g];
    h0v[o] = fmaxf(s, 0.0f);
  }
  float h1v[8];
#pragma unroll
  for (int o = 0; o < 8; ++o) {
    float s = sB1[o];
#pragma unroll
    for (int c = 0; c < 16; ++c) s += sW1[o * 16 + c] * h0v[c];
    h1v[o] = fmaxf(s, 0.0f);
  }
  float s = sSB[0];
#pragma unroll
  for (int c = 0; c < 8; ++c) s += sSW[c] * h1v[c];
  out[t] = 1.0f / (1.0f + __expf(-s));
}

// ---------------------------------------------------------------------------
extern "C" void kernel_launch(void* const* d_in, const int* in_sizes, int n_in,
                              void* d_out, int out_size, void* d_ws, size_t ws_size,
                              hipStream_t stream) {
  const float* ref_feature = (const float*)d_in[0];
  const float* grid    = (const float*)d_in[1];
  const float* conv0_w = (const float*)d_in[2];
  const float* bn0_g   = (const float*)d_in[3];
  const float* bn0_b   = (const float*)d_in[4];
  const float* bn0_m   = (const float*)d_in[5];
  const float* bn0_v   = (const float*)d_in[6];
  const float* conv1_w = (const float*)d_in[7];
  const float* bn1_g   = (const float*)d_in[8];
  const float* bn1_b   = (const float*)d_in[9];
  const float* bn1_m   = (const float*)d_in[10];
  const float* bn1_v   = (const float*)d_in[11];
  const float* sim_w   = (const float*)d_in[12];
  const float* sim_b   = (const float*)d_in[13];
  float* out = (float*)d_out;

  const size_t need = FEATT_BYTES + NWTS * sizeof(float);

  if (ws_size >= need) {
    ushort* featT = (ushort*)d_ws;
    float* wts = (float*)((char*)d_ws + FEATT_BYTES);
    fw_fold<<<1, 64, 0, stream>>>(conv0_w, bn0_g, bn0_b, bn0_m, bn0_v,
                                  conv1_w, bn1_g, bn1_b, bn1_m, bn1_v,
                                  sim_w, sim_b, wts);
    fw_transpose<<<dim3(WW / 64, HH, BB), 256, 0, stream>>>(ref_feature, featT);
    // 256 threads = 4 waves = 256 pixels per block: 1,474,560/256 = 5760.
    fw_main3<<<BB * PIX_PER_B / 256, 256, 0, stream>>>(featT, grid, wts, out);
  } else {
    fw_main_fallback<<<BB * PIX_PER_B / 256, 256, 0, stream>>>(ref_feature, grid,
        conv0_w, bn0_g, bn0_b, bn0_m, bn0_v,
        conv1_w, bn1_g, bn1_b, bn1_m, bn1_v, sim_w, sim_b, out);
  }
}